// Round 3
// baseline (136.288 us; speedup 1.0000x reference)
//
#include <hip/hip_runtime.h>
#include <float.h>
#include <math.h>
#include <stdint.h>

// VQ-VAE VectorQuantizer — round 3: 2-dispatch pipeline, 2x A-frag reuse
//
// z_e: (32, 256, 32, 32) fp32, weight: (1024, 256) fp32
// out: quantized_st (8388608 f32) + loss (1) + perplexity (1)
//
// vq_prep: wsq + codebook A-frag pack (-2*w bf16) + zero counts/loss/done
// vq_main3: grid 512 x 256thr (4 waves). Block = 64 z. Wave (zhalf,chalf):
//   32 z (2 B-sets) x 512 codes (half codebook). Partial argmins combined in
//   LDS; histogram/loss atomics; LAST block computes loss+perplexity outputs.
//
// ws: [0,4096) wsq f32 | [4096,8192) counts u32 | [8192,8200) loss_sum f32, done u32
//     [16384, 16384+524288) cbfrag bf16

#define NB   32
#define NC   256
#define NHW  1024
#define NK   1024
#define NELEM (NB*NC*NHW)
#define GRID_MAIN 512

typedef __attribute__((ext_vector_type(8))) short bf16x8;
typedef __attribute__((ext_vector_type(4))) float f32x4;

__device__ __forceinline__ unsigned short f2bf(float f) {   // RTN fp32->bf16
    unsigned u = __float_as_uint(f);
    u += 0x7FFFu + ((u >> 16) & 1u);
    return (unsigned short)(u >> 16);
}

// ---------------- K1: prep = wsq + pack + zero ----------------
__global__ __launch_bounds__(256) void vq_prep(const float* __restrict__ w,
                                               float* __restrict__ wsq,
                                               unsigned short* __restrict__ cb,
                                               unsigned int* __restrict__ counts,
                                               unsigned int* __restrict__ lossdone) {
    const int tid = threadIdx.x, b = blockIdx.x;
    const int lane = tid & 63, wv = tid >> 6;
    {   // wsq for code k = b*4 + wv
        const int k = b * 4 + wv;
        const float* row = w + k * NC;
        float s = 0.f;
#pragma unroll
        for (int p = 0; p < 4; ++p) { float v = row[lane + p * 64]; s = fmaf(v, v, s); }
#pragma unroll
        for (int off = 32; off; off >>= 1) s += __shfl_down(s, off, 64);
        if (lane == 0) wsq[k] = s;
    }
    // pack: one (tile t, item p) per thread across blocks 0..127
    const int gt = b * 256 + tid;
    if (gt < 32768) {
        const int t = gt >> 9, p = gt & 511;
        const int cc = p >> 6, l = p & 63;
        const int n = l & 15, quad = l >> 4;
        const float* src = w + (t * 16 + n) * NC + cc * 32 + quad * 8;
        const float4 f0 = *(const float4*)src;
        const float4 f1 = *(const float4*)(src + 4);
        union { unsigned short u[8]; uint4 v; } pk;
        pk.u[0] = f2bf(-2.f * f0.x); pk.u[1] = f2bf(-2.f * f0.y);
        pk.u[2] = f2bf(-2.f * f0.z); pk.u[3] = f2bf(-2.f * f0.w);
        pk.u[4] = f2bf(-2.f * f1.x); pk.u[5] = f2bf(-2.f * f1.y);
        pk.u[6] = f2bf(-2.f * f1.z); pk.u[7] = f2bf(-2.f * f1.w);
        *(uint4*)(cb + (size_t)t * 4096 + cc * 512 + (size_t)l * 8) = pk.v;
    }
    if (b == 128) {   // zero counts + loss_sum + done
#pragma unroll
        for (int i = 0; i < 4; ++i) counts[tid * 4 + i] = 0u;
        if (tid < 2) lossdone[tid] = 0u;
    }
}

// ---------------- K2: main ----------------
__global__ __launch_bounds__(256) void vq_main3(const float* __restrict__ z,
                                                const float* __restrict__ w,
                                                const float* __restrict__ wsq,
                                                const unsigned short* __restrict__ cb,
                                                unsigned int* __restrict__ counts,
                                                unsigned int* __restrict__ lossdone,
                                                float* __restrict__ out) {
    __shared__ __align__(16) char cbuf[2][32768];   // double-buffered codebook chunk
    // post-loop aliases into cbuf[0]:
    int*   fidx  = (int*)(cbuf[0]);            // [0,256)   64 ints
    float* pscr  = (float*)(cbuf[0] + 256);    // [256,768) [2][64]
    int*   pidx  = (int*)(cbuf[0] + 768);      // [768,1280)
    float* lred  = (float*)(cbuf[0] + 1280);   // 4 floats
    int*   lflag = (int*)(cbuf[0] + 1296);
    float* red2  = (float*)(cbuf[0] + 1312);   // 4 floats (finalize)

    const int tid  = threadIdx.x;
    const int wv   = tid >> 6, lane = tid & 63;
    const int n    = lane & 15, quad = lane >> 4;
    const int zhalf = wv & 1;        // which 32 of the block's 64 z
    const int chalf = wv >> 1;       // which 512 of the 1024 codes
    const int b   = blockIdx.x;
    const int img = b >> 4;
    const int hw0 = (b & 15) << 6;   // 64 hw per block
    const float* zb = z + (size_t)img * (NC * NHW);
    const char* cbb = (const char*)cb;

    // stage chunk ch: 4 tiles x 8KB = 32KB; slot q = chalf*2 + j holds code
    // tile (chalf*32 + ch*2 + j). 8 loads/thread x 16B.
#define STAGE(ch)                                                              \
    {                                                                          \
        _Pragma("unroll")                                                      \
        for (int i = 0; i < 8; ++i) {                                          \
            const int q = i >> 1, part = i & 1;                                \
            const int tq = (q >> 1) * 32 + (ch) * 2 + (q & 1);                 \
            const char* gsrc = cbb + (size_t)tq * 8192 + part * 4096 + tid * 16;\
            char* ldst = cbuf[(ch) & 1] + i * 4096 + tid * 16;                 \
            __builtin_amdgcn_global_load_lds(                                  \
                (const __attribute__((address_space(1))) unsigned int*)        \
                    (uintptr_t)gsrc,                                           \
                (__attribute__((address_space(3))) unsigned int*)              \
                    (uint32_t)(uintptr_t)ldst,                                 \
                16, 0, 0);                                                     \
        }                                                                      \
    }

    STAGE(0);   // DMA overlaps phase A below

    // ---- Phase A: 2 B-sets (32 z vectors) in registers, bf16 ----
    bf16x8 bfr[2][8];
#pragma unroll
    for (int s = 0; s < 2; ++s) {
#pragma unroll
        for (int cc = 0; cc < 8; ++cc) {
            const float* zp = zb + (size_t)(cc * 32 + quad * 8) * NHW
                              + hw0 + zhalf * 32 + s * 16 + n;
            union { unsigned short u[8]; bf16x8 v; } pk;
#pragma unroll
            for (int j = 0; j < 8; ++j) pk.u[j] = f2bf(zp[(size_t)j * NHW]);
            bfr[s][cc] = pk.v;
        }
    }

    float bestv[2] = {FLT_MAX, FLT_MAX};
    int   besti[2] = {0, 0};

    for (int ch = 0; ch < 16; ++ch) {
        __syncthreads();                    // drains STAGE(ch)
        if (ch + 1 < 16) STAGE(ch + 1);     // prefetch into other buffer
        const char* bufc = cbuf[ch & 1];
        const int kt0 = (chalf * 32 + ch * 2) * 16;
        const int kt1 = kt0 + 16;
        const int slot0 = chalf * 2, slot1 = slot0 + 1;
        f32x4 acc00 = *(const f32x4*)(wsq + kt0 + quad * 4);
        f32x4 acc01 = acc00;
        f32x4 acc10 = *(const f32x4*)(wsq + kt1 + quad * 4);
        f32x4 acc11 = acc10;
#pragma unroll
        for (int cc = 0; cc < 8; ++cc) {    // 2 A-reads feed 4 MFMAs
            const bf16x8 a0 = *(const bf16x8*)(bufc + slot0 * 8192 + cc * 1024 + lane * 16);
            const bf16x8 a1 = *(const bf16x8*)(bufc + slot1 * 8192 + cc * 1024 + lane * 16);
            acc00 = __builtin_amdgcn_mfma_f32_16x16x32_bf16(a0, bfr[0][cc], acc00, 0, 0, 0);
            acc01 = __builtin_amdgcn_mfma_f32_16x16x32_bf16(a0, bfr[1][cc], acc01, 0, 0, 0);
            acc10 = __builtin_amdgcn_mfma_f32_16x16x32_bf16(a1, bfr[0][cc], acc10, 0, 0, 0);
            acc11 = __builtin_amdgcn_mfma_f32_16x16x32_bf16(a1, bfr[1][cc], acc11, 0, 0, 0);
        }
#pragma unroll
        for (int r = 0; r < 4; ++r) {
            const int k0 = kt0 + quad * 4 + r, k1 = kt1 + quad * 4 + r;
            if (acc00[r] < bestv[0]) { bestv[0] = acc00[r]; besti[0] = k0; }
            if (acc01[r] < bestv[1]) { bestv[1] = acc01[r]; besti[1] = k0; }
            if (acc10[r] < bestv[0]) { bestv[0] = acc10[r]; besti[0] = k1; }
            if (acc11[r] < bestv[1]) { bestv[1] = acc11[r]; besti[1] = k1; }
        }
    }

    // cross-quad argmin per set (lanes n, n+16, n+32, n+48)
#pragma unroll
    for (int s = 0; s < 2; ++s) {
        float bv = bestv[s]; int bi = besti[s];
#pragma unroll
        for (int off = 16; off <= 32; off <<= 1) {
            const float ov = __shfl_xor(bv, off, 64);
            const int   ok = __shfl_xor(bi, off, 64);
            if (ov < bv || (ov == bv && ok < bi)) { bv = ov; bi = ok; }
        }
        bestv[s] = bv; besti[s] = bi;
    }
    __syncthreads();
    if (lane < 16) {
#pragma unroll
        for (int s = 0; s < 2; ++s) {
            const int zloc = zhalf * 32 + s * 16 + lane;
            pscr[chalf * 64 + zloc] = bestv[s];
            pidx[chalf * 64 + zloc] = besti[s];
        }
    }
    __syncthreads();
    if (tid < 64) {   // combine the two code-halves; histogram
        const float s0 = pscr[tid], s1 = pscr[64 + tid];
        const int bi = (s1 < s0) ? pidx[64 + tid] : pidx[tid];
        fidx[tid] = bi;
        atomicAdd(&counts[bi], 1u);
    }
    __syncthreads();

    // ---- Phase 2: gather, write quantized, loss ----
    float lsum = 0.f;
    const int hwl = tid & 63;
    const int cg  = tid >> 6;
    const int myk = fidx[hwl];
    const float* wr  = w + myk * NC;
    const float* zp2 = zb + hw0 + hwl;
    float*       op  = out + (size_t)img * (NC * NHW) + hw0 + hwl;
#pragma unroll 4
    for (int p = 0; p < 16; ++p) {
        const int c0 = cg * 64 + p * 4;
        const float4 q4 = *(const float4*)(wr + c0);
        const float qa[4] = {q4.x, q4.y, q4.z, q4.w};
#pragma unroll
        for (int u = 0; u < 4; ++u) {
            const int c = c0 + u;
            const float zv = zp2[(size_t)c * NHW];
            const float d = qa[u] - zv;
            lsum = fmaf(d, d, lsum);
            op[(size_t)c * NHW] = qa[u];
        }
    }
#pragma unroll
    for (int off = 32; off; off >>= 1) lsum += __shfl_down(lsum, off, 64);
    if (lane == 0) lred[wv] = lsum;
    __syncthreads();
    if (tid == 0) {
        atomicAdd((float*)lossdone, lred[0] + lred[1] + lred[2] + lred[3]);
        const unsigned old = __hip_atomic_fetch_add(&lossdone[1], 1u,
                                 __ATOMIC_ACQ_REL, __HIP_MEMORY_SCOPE_AGENT);
        lflag[0] = (old == GRID_MAIN - 1) ? 1 : 0;
    }
    __syncthreads();
    if (lflag[0]) {   // last block finalizes loss + perplexity
        float s = 0.f;
#pragma unroll
        for (int p = 0; p < 4; ++p) {
            const unsigned c = __hip_atomic_load(&counts[tid + p * 256],
                                   __ATOMIC_RELAXED, __HIP_MEMORY_SCOPE_AGENT);
            const float pr = (float)c * (1.f / 32768.f);
            s = fmaf(pr, logf(pr + 1e-10f), s);
        }
#pragma unroll
        for (int off = 32; off; off >>= 1) s += __shfl_down(s, off, 64);
        if (lane == 0) red2[wv] = s;
        __syncthreads();
        if (tid == 0) {
            const float tot = red2[0] + red2[1] + red2[2] + red2[3];
            const float ls = __hip_atomic_load((float*)lossdone,
                                 __ATOMIC_RELAXED, __HIP_MEMORY_SCOPE_AGENT);
            out[NELEM]     = ls * (1.25f / (float)NELEM);
            out[NELEM + 1] = expf(-tot);
        }
    }
}

extern "C" void kernel_launch(void* const* d_in, const int* in_sizes, int n_in,
                              void* d_out, int out_size, void* d_ws, size_t ws_size,
                              hipStream_t stream) {
    const float* z = (const float*)d_in[0];
    const float* w = (const float*)d_in[1];
    float* out = (float*)d_out;

    float*          wsq      = (float*)d_ws;
    unsigned int*   counts   = (unsigned int*)((char*)d_ws + 4096);
    unsigned int*   lossdone = (unsigned int*)((char*)d_ws + 8192);
    unsigned short* cbfrag   = (unsigned short*)((char*)d_ws + 16384);  // 512 KB

    vq_prep <<<256,       256, 0, stream>>>(w, wsq, cbfrag, counts, lossdone);
    vq_main3<<<GRID_MAIN, 256, 0, stream>>>(z, w, wsq, cbfrag, counts, lossdone, out);
}